// Round 19
// baseline (116.008 us; speedup 1.0000x reference)
//
#include <hip/hip_runtime.h>
#include <hip/hip_bf16.h>
#include <stdint.h>

#define B_ 4
#define S_ 2048
#define D_ 512
#define H_ 8
#define HD_ 64
#define M_ (B_*S_)   // 8192

typedef __bf16 bf16x8 __attribute__((ext_vector_type(8)));
typedef float f32x4 __attribute__((ext_vector_type(4)));
typedef float f32x16 __attribute__((ext_vector_type(16)));

__device__ __forceinline__ unsigned short f2b(float f) {
  union { float f; unsigned u; } v; v.f = f;
  unsigned r = v.u + 0x7fff + ((v.u >> 16) & 1);
  return (unsigned short)(r >> 16);
}

__device__ __forceinline__ float b2f(unsigned short u) {
  union { unsigned u; float f; } v; v.u = (unsigned)u << 16;
  return v.f;
}

__device__ __forceinline__ float exp2_hw(float x) {
  return __builtin_amdgcn_exp2f(x);  // v_exp_f32: D = 2^S0
}

__device__ __forceinline__ unsigned cvtpk_bf16(float lo, float hi) {
  unsigned r;
  asm("v_cvt_pk_bf16_f32 %0, %1, %2" : "=v"(r) : "v"(lo), "v"(hi));
  return r;
}

__device__ __forceinline__ void plswap(unsigned &a, unsigned &b) {
  asm volatile("v_permlane32_swap_b32 %0, %1" : "+v"(a), "+v"(b));
}

__device__ __forceinline__ void gload16(const void* g, void* lds) {
  __builtin_amdgcn_global_load_lds(
      (const __attribute__((address_space(1))) unsigned int*)g,
      (__attribute__((address_space(3))) unsigned int*)lds, 16, 0, 0);
}

// ---------------- f32 -> bf16 conversion (x + all 4 weights, one launch) ----------------
#define XN4 (M_ * D_ / 4)
#define WN4 (D_ * D_ / 4)
__global__ __launch_bounds__(256) void cvt_all_kernel(const float* __restrict__ x,
    const float* __restrict__ wq, const float* __restrict__ wk,
    const float* __restrict__ wv, const float* __restrict__ wo,
    unsigned short* __restrict__ xb, unsigned short* __restrict__ wqb,
    unsigned short* __restrict__ wkb, unsigned short* __restrict__ wvb,
    unsigned short* __restrict__ wob) {
  int i = blockIdx.x * blockDim.x + threadIdx.x;
  const float* src; unsigned short* dst; int off;
  if (i < XN4) { src = x; dst = xb; off = i; }
  else {
    int j = i - XN4;
    int sel = j / WN4; off = j - sel * WN4;
    src = (sel == 0) ? wq : (sel == 1) ? wk : (sel == 2) ? wv : wo;
    dst = (sel == 0) ? wqb : (sel == 1) ? wkb : (sel == 2) ? wvb : wob;
  }
  float4 v = ((const float4*)src)[off];
  ushort4 o;
  o.x = f2b(v.x); o.y = f2b(v.y); o.z = f2b(v.z); o.w = f2b(v.w);
  ((ushort4*)dst)[off] = o;
}

// ---------------- mask rank/index precompute: 1 wave per batch ----------------
__global__ __launch_bounds__(64) void rank_kernel(const int* __restrict__ mask,
    int* __restrict__ idx, int* __restrict__ rank, int* __restrict__ nkbuf) {
  int b = blockIdx.x, lane = threadIdx.x;
  const int* mb = mask + (size_t)b * S_;
  int base = 0;
  for (int c = 0; c < 32; ++c) {
    int s = c * 64 + lane;
    int m = mb[s];
    unsigned long long keep = __ballot(m == 0);
    int my = base + __popcll(keep & ((1ull << lane) - 1ull));
    if (m == 0) idx[(size_t)b * S_ + my] = s;    // j -> s
    rank[(size_t)b * S_ + s] = (m == 0) ? my : -1;  // s -> j
    base += __popcll(keep);
  }
  if (lane == 0) nkbuf[b] = base;
}

// ---------------- compact Vt (columns) by idx ----------------
__global__ __launch_bounds__(256) void compact_kernel(
    const unsigned short* __restrict__ Vtb, const int* __restrict__ idx,
    const int* __restrict__ nkbuf, unsigned short* __restrict__ Vtc) {
  int bh = blockIdx.y, b = bh >> 3;
  int nk = nkbuf[b];
  const int* ib = idx + (size_t)b * S_;
  int tid = threadIdx.x;
  int d = blockIdx.x;
  const unsigned short* src = &Vtb[((size_t)bh * HD_ + d) * S_];
  unsigned short* dst = &Vtc[((size_t)bh * HD_ + d) * S_];
  int j0 = tid * 8;
  if (j0 < nk) {
    unsigned short tmp[8];
    #pragma unroll
    for (int c = 0; c < 8; ++c) {
      int j = j0 + c;
      tmp[c] = (j < nk) ? src[ib[j]] : (unsigned short)0;
    }
    *(uint4*)&dst[j0] = *(uint4*)tmp;
  }
}

// ------- GEMM core, double-buffered: C[128x128] = A[128xK] * B^T, BK=64, prefetch-next -------
__device__ __forceinline__ void gemm_core_db(const unsigned short* __restrict__ A,
                                             const unsigned short* __restrict__ W,
                                             int m0, int n0, f32x4 (&acc)[4][4],
                                             unsigned short (&As)[2][128 * 64],
                                             unsigned short (&Bs)[2][128 * 64]) {
  int tid = threadIdx.x;
  int w = tid >> 6, lane = tid & 63;
  int l15 = lane & 15, g = lane >> 4;
  int wr = w >> 1, wc = w & 1;
  #define STAGE_G(buf, k0_) do {                                               \
    _Pragma("unroll")                                                          \
    for (int i = 0; i < 4; ++i) {                                              \
      int l = i * 256 + w * 64 + lane;                                         \
      int row = l >> 3, seg = l & 7;                                           \
      int sseg = seg ^ (row & 7);                                              \
      gload16(A + (size_t)(m0 + row) * D_ + (k0_) + sseg * 8,                  \
              (char*)As[buf] + (size_t)(i * 256 + w * 64) * 16);               \
      gload16(W + (size_t)(n0 + row) * D_ + (k0_) + sseg * 8,                  \
              (char*)Bs[buf] + (size_t)(i * 256 + w * 64) * 16);               \
    }                                                                          \
  } while (0)
  STAGE_G(0, 0);
  __syncthreads();
  for (int ks = 0; ks < 8; ++ks) {
    int cur = ks & 1;
    if (ks < 7) STAGE_G(cur ^ 1, (ks + 1) * 64);
    #pragma unroll
    for (int kk = 0; kk < 2; ++kk) {
      int sw = ((kk * 4 + g) ^ (l15 & 7)) * 8;
      bf16x8 af[4], bfr[4];
      #pragma unroll
      for (int t = 0; t < 4; ++t) {
        af[t]  = *(const bf16x8*)&As[cur][(wr * 64 + t * 16 + l15) * 64 + sw];
        bfr[t] = *(const bf16x8*)&Bs[cur][(wc * 64 + t * 16 + l15) * 64 + sw];
      }
      #pragma unroll
      for (int mi = 0; mi < 4; ++mi)
        #pragma unroll
        for (int ni = 0; ni < 4; ++ni)
          acc[mi][ni] = __builtin_amdgcn_mfma_f32_16x16x32_bf16(af[mi], bfr[ni], acc[mi][ni], 0, 0, 0);
    }
    __syncthreads();
  }
  #undef STAGE_G
}

// ---- QKV projection, A-RESIDENT: block owns (m0=64 rows, n0=128 cols); x-tile loaded once
// ---- into LDS (8 chunks of [64][64]); loops z=Q,K,V streaming only B-tiles (dbuf).
__global__ __launch_bounds__(256) void gemm_qkv(const unsigned short* __restrict__ xb,
    const unsigned short* __restrict__ wqb, const unsigned short* __restrict__ wkb,
    const unsigned short* __restrict__ wvb,
    const float* __restrict__ bq, const float* __restrict__ bk, const float* __restrict__ bv,
    const float* __restrict__ tptr, const int* __restrict__ rank,
    unsigned short* __restrict__ Qb, unsigned short* __restrict__ Kc, unsigned short* __restrict__ Vtb) {
  __shared__ unsigned short Alds[8][64 * 64];    // 64 KB: A chunks, persistent
  __shared__ unsigned short Blds[2][128 * 64];   // 32 KB: B double-buffer
  int tid = threadIdx.x;
  int w = tid >> 6, lane = tid & 63;
  int l15 = lane & 15, g = lane >> 4;
  int m0 = blockIdx.x * 64, n0 = blockIdx.y * 128;
  const unsigned short* Ws[3] = {wqb, wkb, wvb};
  const float* biases[3] = {bq, bk, bv};
  float qscale = tptr[0] * 1.44269504088896340736f;

  #define STAGE_A(ck) do {                                                     \
    _Pragma("unroll")                                                          \
    for (int i = 0; i < 2; ++i) {                                              \
      int l = i * 256 + w * 64 + lane;                                         \
      int row = l >> 3, seg = l & 7;                                           \
      int sseg = seg ^ (row & 7);                                              \
      gload16(xb + (size_t)(m0 + row) * D_ + (ck) * 64 + sseg * 8,             \
              (char*)&Alds[ck][0] + (size_t)(i * 256 + w * 64) * 16);          \
    }                                                                          \
  } while (0)
  #define STAGE_B(buf, Wp, k0_) do {                                           \
    _Pragma("unroll")                                                          \
    for (int i = 0; i < 4; ++i) {                                              \
      int l = i * 256 + w * 64 + lane;                                         \
      int row = l >> 3, seg = l & 7;                                           \
      int sseg = seg ^ (row & 7);                                              \
      gload16((Wp) + (size_t)(n0 + row) * D_ + (k0_) + sseg * 8,               \
              (char*)&Blds[buf][0] + (size_t)(i * 256 + w * 64) * 16);         \
    }                                                                          \
  } while (0)

  #pragma unroll
  for (int ck = 0; ck < 8; ++ck) STAGE_A(ck);
  STAGE_B(0, Ws[0], 0);
  __syncthreads();

  #pragma unroll
  for (int z = 0; z < 3; ++z) {
    f32x4 zero4 = {0.f, 0.f, 0.f, 0.f};
    f32x4 acc[4][2];
    #pragma unroll
    for (int mi = 0; mi < 4; ++mi)
      #pragma unroll
      for (int ni = 0; ni < 2; ++ni) acc[mi][ni] = zero4;
    for (int ks = 0; ks < 8; ++ks) {
      int cur = ks & 1;
      if (ks < 7) STAGE_B(cur ^ 1, Ws[z], (ks + 1) * 64);
      else if (z < 2) STAGE_B(cur ^ 1, Ws[z + 1], 0);
      #pragma unroll
      for (int kk = 0; kk < 2; ++kk) {
        int sw = ((kk * 4 + g) ^ (l15 & 7)) * 8;
        bf16x8 af[4], bfr[2];
        #pragma unroll
        for (int t = 0; t < 4; ++t)
          af[t] = *(const bf16x8*)&Alds[ks][(t * 16 + l15) * 64 + sw];
        #pragma unroll
        for (int ni = 0; ni < 2; ++ni)
          bfr[ni] = *(const bf16x8*)&Blds[cur][(w * 32 + ni * 16 + l15) * 64 + sw];
        #pragma unroll
        for (int mi = 0; mi < 4; ++mi)
          #pragma unroll
          for (int ni = 0; ni < 2; ++ni)
            acc[mi][ni] = __builtin_amdgcn_mfma_f32_16x16x32_bf16(af[mi], bfr[ni], acc[mi][ni], 0, 0, 0);
      }
      __syncthreads();
    }
    // ---- epilogue for this z ----
    if (z == 2) {
      // V: acc -> T[e][s ^ ((e&7)<<3)] (reuse Alds region, 128x64 shorts), then coalesced store
      unsigned short* T = &Alds[0][0];
      #pragma unroll
      for (int mi = 0; mi < 4; ++mi)
        #pragma unroll
        for (int ni = 0; ni < 2; ++ni) {
          int el = w * 32 + ni * 16 + l15;
          float bb = biases[2][n0 + el];
          int sx = (el & 7) << 3;
          #pragma unroll
          for (int r = 0; r < 4; ++r) {
            int s = mi * 16 + g * 4 + r;
            T[el * 64 + (s ^ sx)] = f2b(acc[mi][ni][r] + bb);
          }
        }
      __syncthreads();
      int el = tid >> 1, hf = tid & 1;
      int eg = n0 + el, h = eg >> 6, dd = eg & 63;
      int bI = m0 >> 11, sbase = (m0 & 2047) + hf * 32;
      unsigned short* dst = &Vtb[((size_t)(bI * H_ + h) * HD_ + dd) * S_ + sbase];
      const unsigned short* srcR = &T[el * 64];
      int jx = el & 7;
      #pragma unroll
      for (int c = 0; c < 4; ++c) {
        int cc = (hf * 4 + c) ^ jx;
        uint4 v = *(const uint4*)&srcR[cc * 8];
        *(uint4*)&dst[c * 8] = v;
      }
    } else if (z == 1) {
      // K: write rows at compacted position j = rank[s]
      #pragma unroll
      for (int mi = 0; mi < 4; ++mi)
        #pragma unroll
        for (int ni = 0; ni < 2; ++ni) {
          int e = n0 + w * 32 + ni * 16 + l15;
          float bb = biases[1][e];
          int h = e >> 6, dd = e & 63;
          #pragma unroll
          for (int r = 0; r < 4; ++r) {
            int m = m0 + mi * 16 + g * 4 + r;
            int b = m >> 11, s = m & 2047;
            int jj = rank[(size_t)b * S_ + s];
            if (jj >= 0) {
              unsigned short u = f2b(acc[mi][ni][r] + bb);
              Kc[((size_t)(b * H_ + h) * S_ + jj) * HD_ + dd] = u;
            }
          }
        }
    } else {
      // Q (pre-scaled)
      #pragma unroll
      for (int mi = 0; mi < 4; ++mi)
        #pragma unroll
        for (int ni = 0; ni < 2; ++ni) {
          int e = n0 + w * 32 + ni * 16 + l15;
          float bb = biases[0][e];
          int h = e >> 6, dd = e & 63;
          #pragma unroll
          for (int r = 0; r < 4; ++r) {
            int m = m0 + mi * 16 + g * 4 + r;
            int b = m >> 11, s = m & 2047;
            unsigned short u = f2b((acc[mi][ni][r] + bb) * qscale);
            Qb[((size_t)(b * H_ + h) * S_ + s) * HD_ + dd] = u;
          }
        }
    }
  }
  #undef STAGE_A
  #undef STAGE_B
}

// ---------------- output projection -> bf16 tmp ----------------
__global__ __launch_bounds__(256) void gemm_proj(const unsigned short* __restrict__ AOb,
    const unsigned short* __restrict__ wob, const float* __restrict__ bo,
    unsigned short* __restrict__ Pfb) {
  __shared__ unsigned short As[2][128 * 64], Bs[2][128 * 64];
  int m0 = blockIdx.x * 128, n0 = blockIdx.y * 128;
  f32x4 zero4 = {0.f, 0.f, 0.f, 0.f};
  f32x4 acc[4][4];
  #pragma unroll
  for (int mi = 0; mi < 4; ++mi)
    #pragma unroll
    for (int ni = 0; ni < 4; ++ni) acc[mi][ni] = zero4;
  gemm_core_db(AOb, wob, m0, n0, acc, As, Bs);
  int tid = threadIdx.x;
  int w = tid >> 6, lane = tid & 63, l15 = lane & 15, g = lane >> 4;
  int wr = w >> 1, wc = w & 1;
  #pragma unroll
  for (int mi = 0; mi < 4; ++mi)
    #pragma unroll
    for (int ni = 0; ni < 4; ++ni) {
      int e = n0 + wc * 64 + ni * 16 + l15;
      float bb = bo[e];
      #pragma unroll
      for (int r = 0; r < 4; ++r) {
        int m = m0 + wr * 64 + mi * 16 + g * 4 + r;
        Pfb[(size_t)m * D_ + e] = f2b(acc[mi][ni][r] + bb);
      }
    }
}

// ---- flash attention over COMPACTED keys: swapped QK^T 32x32x16, in-register P,
// ---- cross-tile pipeline, tail keep-mask (j < nk), XCD-grouped bh assignment.
__global__ __launch_bounds__(256, 2) void attn_kernel(const unsigned short* __restrict__ Qb,
    const unsigned short* __restrict__ Kc, const unsigned short* __restrict__ Vtc,
    const int* __restrict__ nkbuf, unsigned short* __restrict__ AOb) {
  __shared__ unsigned short Ks[3][64 * 64], Vs[3][64 * 64];
  __shared__ uint4 mlds[32][4][2];   // [tile][kp][hi] : keep-mask words for pa
  int bid = blockIdx.y * gridDim.x + blockIdx.x;
  int xcd = bid & 7, jj = bid >> 3;
  int bh = xcd * 4 + (jj >> 4);
  int qblk = jj & 15;
  int b = bh >> 3, h = bh & 7;
  int tid = threadIdx.x, w = tid >> 6, lane = tid & 63;
  int l31 = lane & 31, hi = lane >> 5;
  int q0w = qblk * 128 + w * 32;
  const unsigned short* Qbase = Qb + (size_t)bh * S_ * HD_;
  int nk = nkbuf[b];
  int nt = (nk + 63) >> 6;

  // Q as B-frag (32x32x16); Q is pre-scaled by temp*log2(e)
  bf16x8 qf[4];
  #pragma unroll
  for (int kk = 0; kk < 4; ++kk)
    qf[kk] = *(const bf16x8*)&Qbase[(size_t)(q0w + l31) * HD_ + kk * 16 + hi * 8];

  bf16x8 ones;
  #pragma unroll
  for (int c = 0; c < 8; ++c) ones[c] = (__bf16)1.0f;

  f32x16 out[2], lacc, zc;
  #pragma unroll
  for (int i = 0; i < 16; ++i) { out[0][i] = 0.f; out[1][i] = 0.f; lacc[i] = 0.f; zc[i] = 0.f; }

  f32x16 stA[2], stB[2];

  #define STAGE_KV(buf, kb_) do {                                              \
    _Pragma("unroll")                                                          \
    for (int i = 0; i < 2; ++i) {                                              \
      int l = i * 256 + w * 64 + lane;                                         \
      int row = l >> 3, seg = l & 7;                                           \
      int sseg = seg ^ (row & 7);                                              \
      gload16(Kc + ((size_t)bh * S_ + (kb_) + row) * HD_ + sseg * 8,           \
              (char*)Ks[buf] + (size_t)(i * 256 + w * 64) * 16);               \
      gload16(Vtc + ((size_t)bh * HD_ + row) * S_ + (kb_) + sseg * 8,          \
              (char*)Vs[buf] + (size_t)(i * 256 + w * 64) * 16);               \
    }                                                                          \
  } while (0)

  #define QKT_TILE(KSBUF, ST) do {                                             \
    __builtin_amdgcn_s_setprio(1);                                             \
    const unsigned short* kbase_ = Ks[KSBUF];                                  \
    _Pragma("unroll")                                                          \
    for (int kk = 0; kk < 4; ++kk) {                                           \
      int sw = ((2 * kk + hi) ^ (l31 & 7)) * 8;                                \
      bf16x8 ka0 = *(const bf16x8*)&kbase_[l31 * 64 + sw];                     \
      bf16x8 ka1 = *(const bf16x8*)&kbase_[(32 + l31) * 64 + sw];              \
      ST[0] = __builtin_amdgcn_mfma_f32_32x32x16_bf16(ka0, qf[kk], kk ? ST[0] : zc, 0, 0, 0); \
      ST[1] = __builtin_amdgcn_mfma_f32_32x32x16_bf16(ka1, qf[kk], kk ? ST[1] : zc, 0, 0, 0); \
    }                                                                          \
    __builtin_amdgcn_s_setprio(0);                                             \
  } while (0)

  // BODY(T): barrier; stage T+2; QKT(T+1)->STN; exp2(STC); PV(T) with packed-AND masking.
  #define TILE_BODY(T, STC, STN, bPV, bQK, bST) do {                           \
    __syncthreads();                                                           \
    if ((T) + 2 < nt) STAGE_KV(bST, ((T) + 2) * 64);                           \
    if ((T) + 1 < nt) QKT_TILE(bQK, STN);                                      \
    _Pragma("unroll")                                                          \
    for (int ktile = 0; ktile < 2; ++ktile)                                    \
      _Pragma("unroll")                                                        \
      for (int reg = 0; reg < 16; ++reg)                                       \
        STC[ktile][reg] = exp2_hw(STC[ktile][reg]);                            \
    __builtin_amdgcn_s_setprio(1);                                             \
    const unsigned short* vbase_ = Vs[bPV];                                    \
    _Pragma("unroll")                                                          \
    for (int kp = 0; kp < 4; ++kp) {                                           \
      const int kt8 = kp >> 1;                                                 \
      const int ro = 8 * (kp & 1);                                             \
      uint4 mw = mlds[(T)][kp][hi];                                            \
      unsigned Xa = cvtpk_bf16(STC[kt8][ro + 0], STC[kt8][ro + 1]);            \
      unsigned Ya = cvtpk_bf16(STC[kt8][ro + 4], STC[kt8][ro + 5]);            \
      unsigned Xb = cvtpk_bf16(STC[kt8][ro + 2], STC[kt8][ro + 3]);            \
      unsigned Yb = cvtpk_bf16(STC[kt8][ro + 6], STC[kt8][ro + 7]);            \
      plswap(Xa, Ya);                                                          \
      plswap(Xb, Yb);                                                          \
      union { unsigned u[4]; bf16x8 v; } pu;                                   \
      pu.u[0] = Xa & mw.x; pu.u[1] = Xb & mw.y;                                \
      pu.u[2] = Ya & mw.z; pu.u[3] = Yb & mw.w;                                \
      bf16x8 pa = pu.v;                                                        \
      _Pragma("unroll")                                                        \
      for (int dn = 0; dn < 2; ++dn) {                                         \
        int row = dn * 32 + l31;                                               \
        bf16x8 vb = *(const bf16x8*)&vbase_[row * 64 + ((2 * kp + hi) ^ (row & 7)) * 8]; \
        out[dn] = __builtin_amdgcn_mfma_f32_32x32x16_bf16(pa, vb, out[dn], 0, 0, 0); \
      }                                                                        \
      lacc = __builtin_amdgcn_mfma_f32_32x32x16_bf16(pa, ones, lacc, 0, 0, 0); \
    }                                                                          \
    __builtin_amdgcn_s_setprio(0);                                             \
  } while (0)

  // ---- prologue: stage 0,1; build tail keep-mask table (keep iff key j < nk); QKT(0) ----
  STAGE_KV(0, 0);
  {
    int t = tid;
    int tile = t >> 3, kp = (t >> 1) & 3, hh = t & 1;
    int j0 = tile * 64 + kp * 16 + hh * 8;
    uint4 mw;
    mw.x = ((j0 + 0 < nk) ? 0x0000FFFFu : 0u) | ((j0 + 1 < nk) ? 0xFFFF0000u : 0u);
    mw.y = ((j0 + 2 < nk) ? 0x0000FFFFu : 0u) | ((j0 + 3 < nk) ? 0xFFFF0000u : 0u);
    mw.z = ((j0 + 4 < nk) ? 0x0000FFFFu : 0u) | ((j0 + 5 < nk) ? 0xFFFF0000u : 0u);
    mw.w = ((j0 + 6 < nk) ? 0x0000FFFFu : 0u) | ((j0 + 7 < nk) ? 0xFFFF0000u : 0u);
    mlds[tile][kp][hh] = mw;
  }
  __syncthreads();
  if (nt > 1) STAGE_KV(1, 64);
  QKT_TILE(0, stA);

  int t = 0;
  for (; t + 1 < nt; t += 2) {
    TILE_BODY(t, stA, stB, t % 3, (t + 1) % 3, (t + 2) % 3);
    TILE_BODY(t + 1, stB, stA, (t + 1) % 3, (t + 2) % 3, t % 3);
  }
  if (t < nt) TILE_BODY(t, stA, stB, t % 3, (t + 1) % 3, (t + 2) % 3);

  // ---- epilogue: out[q = q0w + crow][d = dn*32 + l31] / lsum[q] ----
  #pragma unroll
  for (int reg = 0; reg < 16; ++reg) {
    float inv = 1.f / lacc[reg];
    int q = q0w + (reg & 3) + 8 * (reg >> 2) + 4 * hi;
    #pragma unroll
    for (int dn = 0; dn < 2; ++dn)
      AOb[((size_t)b * S_ + q) * D_ + h * HD_ + dn * 32 + l31] = f2b(out[dn][reg] * inv);
  }
  #undef TILE_BODY
  #undef QKT_TILE
  #undef STAGE_KV
}

// ---------------- residual + LayerNorm (proj tmp in bf16) ----------------
__global__ __launch_bounds__(256) void ln_kernel(const unsigned short* __restrict__ Pfb,
    const float* __restrict__ x, const float* __restrict__ gamma,
    const float* __restrict__ beta, float* __restrict__ out) {
  int row = blockIdx.x * 4 + (threadIdx.x >> 6);
  int lane = threadIdx.x & 63;
  const unsigned short* pr = Pfb + (size_t)row * D_;
  const float* xr = x + (size_t)row * D_;
  ushort4 p0 = *(const ushort4*)(pr + lane * 8);
  ushort4 p1 = *(const ushort4*)(pr + lane * 8 + 4);
  float4 b0 = *(const float4*)(xr + lane * 8);
  float4 b1 = *(const float4*)(xr + lane * 8 + 4);
  float y[8] = {b2f(p0.x) + b0.x, b2f(p0.y) + b0.y, b2f(p0.z) + b0.z, b2f(p0.w) + b0.w,
                b2f(p1.x) + b1.x, b2f(p1.y) + b1.y, b2f(p1.z) + b1.z, b2f(p1.w) + b1.w};
  float s = 0.f, s2 = 0.f;
  #pragma unroll
  for (int i = 0; i < 8; ++i) { s += y[i]; s2 += y[i] * y[i]; }
  #pragma unroll
  for (int d = 1; d < 64; d <<= 1) { s += __shfl_xor(s, d); s2 += __shfl_xor(s2, d); }
  float mu = s * (1.f / 512.f);
  float var = s2 * (1.f / 512.f) - mu * mu;
  float inv = rsqrtf(fmaxf(var, 0.f) + 1e-6f);
  float4 g0 = *(const float4*)(gamma + lane * 8);
  float4 g1 = *(const float4*)(gamma + lane * 8 + 4);
  float4 e0 = *(const float4*)(beta + lane * 8);
  float4 e1 = *(const float4*)(beta + lane * 8 + 4);
  float* orow = out + (size_t)row * D_;
  float4 o0 = {(y[0] - mu) * inv * g0.x + e0.x, (y[1] - mu) * inv * g0.y + e0.y,
               (y[2] - mu) * inv * g0.z + e0.z, (y[3] - mu) * inv * g0.w + e0.w};
  float4 o1 = {(y[4] - mu) * inv * g1.x + e1.x, (y[5] - mu) * inv * g1.y + e1.y,
               (y[6] - mu) * inv * g1.z + e1.z, (y[7] - mu) * inv * g1.w + e1.w};
  *(float4*)(orow + lane * 8) = o0;
  *(float4*)(orow + lane * 8 + 4) = o1;
}

extern "C" void kernel_launch(void* const* d_in, const int* in_sizes, int n_in,
                              void* d_out, int out_size, void* d_ws, size_t ws_size,
                              hipStream_t stream) {
  const float* x = (const float*)d_in[0];
  const int* mask = (const int*)d_in[1];
  const float* wq = (const float*)d_in[2];
  const float* bq = (const float*)d_in[3];
  const float* wk = (const float*)d_in[4];
  const float* bk = (const float*)d_in[5];
  const float* wv = (const float*)d_in[6];
  const float* bv = (const float*)d_in[7];
  const float* wo = (const float*)d_in[8];
  const float* bo = (const float*)d_in[9];
  const float* gamma = (const float*)d_in[10];
  const float* beta = (const float*)d_in[11];
  const float* temp = (const float*)d_in[12];
  float* out = (float*)d_out;
  char* ws = (char*)d_ws;
  const size_t MB = (size_t)1 << 20;
  unsigned short* xb  = (unsigned short*)(ws);                    // 8 MB
  unsigned short* wqb = (unsigned short*)(ws + 8 * MB);           // 0.5 MB
  unsigned short* wkb = (unsigned short*)(ws + 8 * MB + 512 * 1024);
  unsigned short* wvb = (unsigned short*)(ws + 9 * MB);
  unsigned short* wob = (unsigned short*)(ws + 9 * MB + 512 * 1024);
  unsigned short* Qb  = (unsigned short*)(ws + 10 * MB);          // 8 MB
  unsigned short* Pfb = (unsigned short*)(ws + 18 * MB);          // 8 MB bf16
  unsigned short* Vtb = (unsigned short*)(ws + 26 * MB);          // 8 MB
  unsigned short* AOb = (unsigned short*)(ws + 34 * MB);          // 8 MB
  unsigned short* Kc  = (unsigned short*)(ws + 42 * MB);          // 8 MB compacted K
  unsigned short* Vtc = (unsigned short*)(ws + 50 * MB);          // 8 MB compacted Vt
  int*            idx = (int*)(ws + 58 * MB);                     // 32 KB
  int*            rnk = (int*)(ws + 58 * MB + 64 * 1024);         // 32 KB
  int*            nkb = (int*)(ws + 58 * MB + 128 * 1024);        // 16 B

  cvt_all_kernel<<<(XN4 + 4 * WN4 + 255) / 256, 256, 0, stream>>>(
      x, wq, wk, wv, wo, xb, wqb, wkb, wvb, wob);
  rank_kernel<<<4, 64, 0, stream>>>(mask, idx, rnk, nkb);
  gemm_qkv<<<dim3(128, 4), 256, 0, stream>>>(xb, wqb, wkb, wvb, bq, bk, bv, temp, rnk, Qb, Kc, Vtb);
  compact_kernel<<<dim3(64, 32), 256, 0, stream>>>(Vtb, idx, nkb, Vtc);
  attn_kernel<<<dim3(16, 32), 256, 0, stream>>>(Qb, Kc, Vtc, nkb, AOb);
  gemm_proj<<<dim3(64, 4), 256, 0, stream>>>(AOb, wob, bo, Pfb);
  ln_kernel<<<2048, 256, 0, stream>>>(Pfb, x, gamma, beta, out);
}

// Round 20
// 100.739 us; speedup vs baseline: 1.1516x; 1.1516x over previous
//
#include <hip/hip_runtime.h>
#include <hip/hip_bf16.h>
#include <stdint.h>

#define B_ 4
#define S_ 2048
#define D_ 512
#define H_ 8
#define HD_ 64
#define M_ (B_*S_)   // 8192

typedef __bf16 bf16x8 __attribute__((ext_vector_type(8)));
typedef float f32x4 __attribute__((ext_vector_type(4)));
typedef float f32x16 __attribute__((ext_vector_type(16)));

__device__ __forceinline__ unsigned short f2b(float f) {
  union { float f; unsigned u; } v; v.f = f;
  unsigned r = v.u + 0x7fff + ((v.u >> 16) & 1);
  return (unsigned short)(r >> 16);
}

__device__ __forceinline__ float b2f(unsigned short u) {
  union { unsigned u; float f; } v; v.u = (unsigned)u << 16;
  return v.f;
}

__device__ __forceinline__ float exp2_hw(float x) {
  return __builtin_amdgcn_exp2f(x);  // v_exp_f32: D = 2^S0
}

__device__ __forceinline__ unsigned cvtpk_bf16(float lo, float hi) {
  unsigned r;
  asm("v_cvt_pk_bf16_f32 %0, %1, %2" : "=v"(r) : "v"(lo), "v"(hi));
  return r;
}

__device__ __forceinline__ void plswap(unsigned &a, unsigned &b) {
  asm volatile("v_permlane32_swap_b32 %0, %1" : "+v"(a), "+v"(b));
}

__device__ __forceinline__ void gload16(const void* g, void* lds) {
  __builtin_amdgcn_global_load_lds(
      (const __attribute__((address_space(1))) unsigned int*)g,
      (__attribute__((address_space(3))) unsigned int*)lds, 16, 0, 0);
}

// ---------------- f32 -> bf16 conversion (x + all 4 weights, one launch) ----------------
#define XN4 (M_ * D_ / 4)
#define WN4 (D_ * D_ / 4)
__global__ __launch_bounds__(256) void cvt_all_kernel(const float* __restrict__ x,
    const float* __restrict__ wq, const float* __restrict__ wk,
    const float* __restrict__ wv, const float* __restrict__ wo,
    unsigned short* __restrict__ xb, unsigned short* __restrict__ wqb,
    unsigned short* __restrict__ wkb, unsigned short* __restrict__ wvb,
    unsigned short* __restrict__ wob) {
  int i = blockIdx.x * blockDim.x + threadIdx.x;
  const float* src; unsigned short* dst; int off;
  if (i < XN4) { src = x; dst = xb; off = i; }
  else {
    int j = i - XN4;
    int sel = j / WN4; off = j - sel * WN4;
    src = (sel == 0) ? wq : (sel == 1) ? wk : (sel == 2) ? wv : wo;
    dst = (sel == 0) ? wqb : (sel == 1) ? wkb : (sel == 2) ? wvb : wob;
  }
  float4 v = ((const float4*)src)[off];
  ushort4 o;
  o.x = f2b(v.x); o.y = f2b(v.y); o.z = f2b(v.z); o.w = f2b(v.w);
  ((ushort4*)dst)[off] = o;
}

// ---------------- mask rank/index precompute: 1 wave per batch ----------------
__global__ __launch_bounds__(64) void rank_kernel(const int* __restrict__ mask,
    int* __restrict__ idx, int* __restrict__ rank, int* __restrict__ nkbuf) {
  int b = blockIdx.x, lane = threadIdx.x;
  const int* mb = mask + (size_t)b * S_;
  int base = 0;
  for (int c = 0; c < 32; ++c) {
    int s = c * 64 + lane;
    int m = mb[s];
    unsigned long long keep = __ballot(m == 0);
    int my = base + __popcll(keep & ((1ull << lane) - 1ull));
    if (m == 0) idx[(size_t)b * S_ + my] = s;    // j -> s
    rank[(size_t)b * S_ + s] = (m == 0) ? my : -1;  // s -> j
    base += __popcll(keep);
  }
  if (lane == 0) nkbuf[b] = base;
}

// ---------------- compact Vt (columns) by idx ----------------
__global__ __launch_bounds__(256) void compact_kernel(
    const unsigned short* __restrict__ Vtb, const int* __restrict__ idx,
    const int* __restrict__ nkbuf, unsigned short* __restrict__ Vtc) {
  int bh = blockIdx.y, b = bh >> 3;
  int nk = nkbuf[b];
  const int* ib = idx + (size_t)b * S_;
  int tid = threadIdx.x;
  int d = blockIdx.x;
  const unsigned short* src = &Vtb[((size_t)bh * HD_ + d) * S_];
  unsigned short* dst = &Vtc[((size_t)bh * HD_ + d) * S_];
  int j0 = tid * 8;
  if (j0 < nk) {
    unsigned short tmp[8];
    #pragma unroll
    for (int c = 0; c < 8; ++c) {
      int j = j0 + c;
      tmp[c] = (j < nk) ? src[ib[j]] : (unsigned short)0;
    }
    *(uint4*)&dst[j0] = *(uint4*)tmp;
  }
}

// ------- GEMM core, double-buffered BK=32: C[128x128] = A[128xK] * B^T -------
// SH layout (shorts): A bufs at 0 / 4096, B bufs at 8192 / 12288 (total 16384 = 32 KB).
__device__ __forceinline__ void gemm_core_db32(const unsigned short* __restrict__ A,
                                               const unsigned short* __restrict__ W,
                                               int m0, int n0, f32x4 (&acc)[4][4],
                                               unsigned short* SH) {
  int tid = threadIdx.x;
  int w = tid >> 6, lane = tid & 63;
  int l15 = lane & 15, g = lane >> 4;
  int wr = w >> 1, wc = w & 1;
  #define STAGE32(ab, buf, P, r0_, k0_) do {                                   \
    _Pragma("unroll")                                                          \
    for (int i = 0; i < 2; ++i) {                                              \
      int l = i * 256 + tid;                                                   \
      int row = l >> 2, seg = l & 3;                                           \
      int sseg = seg ^ (row & 3);                                              \
      gload16((P) + (size_t)((r0_) + row) * D_ + (k0_) + sseg * 8,             \
              (char*)(SH + (ab) * 8192 + (buf) * 4096) + (size_t)l * 16);      \
    }                                                                          \
  } while (0)
  STAGE32(0, 0, A, m0, 0);
  STAGE32(1, 0, W, n0, 0);
  __syncthreads();
  for (int ks = 0; ks < 16; ++ks) {
    int cur = ks & 1;
    if (ks < 15) {
      STAGE32(0, cur ^ 1, A, m0, (ks + 1) * 32);
      STAGE32(1, cur ^ 1, W, n0, (ks + 1) * 32);
    }
    bf16x8 af[4], bfr[4];
    #pragma unroll
    for (int t = 0; t < 4; ++t) {
      int ra = wr * 64 + t * 16 + l15;
      af[t]  = *(const bf16x8*)&SH[cur * 4096 + ra * 32 + ((g ^ (ra & 3)) * 8)];
      int rb = wc * 64 + t * 16 + l15;
      bfr[t] = *(const bf16x8*)&SH[8192 + cur * 4096 + rb * 32 + ((g ^ (rb & 3)) * 8)];
    }
    #pragma unroll
    for (int mi = 0; mi < 4; ++mi)
      #pragma unroll
      for (int ni = 0; ni < 4; ++ni)
        acc[mi][ni] = __builtin_amdgcn_mfma_f32_16x16x32_bf16(af[mi], bfr[ni], acc[mi][ni], 0, 0, 0);
    __syncthreads();
  }
  #undef STAGE32
}

// ---- QKV projection, grid (64,4,3); Q pre-scaled; K written compacted via rank; V via LDS ----
__global__ __launch_bounds__(256) void gemm_qkv(const unsigned short* __restrict__ xb,
    const unsigned short* __restrict__ wqb, const unsigned short* __restrict__ wkb,
    const unsigned short* __restrict__ wvb,
    const float* __restrict__ bq, const float* __restrict__ bk, const float* __restrict__ bv,
    const float* __restrict__ tptr, const int* __restrict__ rank,
    unsigned short* __restrict__ Qb, unsigned short* __restrict__ Kc, unsigned short* __restrict__ Vtb) {
  __shared__ unsigned short SH[16384];   // 32 KB: GEMM bufs; reused as V-transpose scratch
  int z = blockIdx.z;
  const unsigned short* W = (z == 0) ? wqb : ((z == 1) ? wkb : wvb);
  const float* bias = (z == 0) ? bq : ((z == 1) ? bk : bv);
  float scale = (z == 0) ? tptr[0] * 1.44269504088896340736f : 1.0f;
  int m0 = blockIdx.x * 128, n0 = blockIdx.y * 128;
  f32x4 zero4 = {0.f, 0.f, 0.f, 0.f};
  f32x4 acc[4][4];
  #pragma unroll
  for (int mi = 0; mi < 4; ++mi)
    #pragma unroll
    for (int ni = 0; ni < 4; ++ni) acc[mi][ni] = zero4;
  gemm_core_db32(xb, W, m0, n0, acc, SH);
  int tid = threadIdx.x;
  int w = tid >> 6, lane = tid & 63, l15 = lane & 15, g = lane >> 4;
  int wr = w >> 1, wc = w & 1;
  if (z == 2) {
    // ---- V: acc -> LDS T[e][s ^ ((e&15)<<3)] bf16 (T = SH, [128][128]), coalesced store ----
    unsigned short* T = SH;
    #pragma unroll
    for (int mi = 0; mi < 4; ++mi)
      #pragma unroll
      for (int ni = 0; ni < 4; ++ni) {
        int el = wc * 64 + ni * 16 + l15;
        float bb = bias[n0 + el];
        int sx = (el & 15) << 3;
        #pragma unroll
        for (int r = 0; r < 4; ++r) {
          int s = wr * 64 + mi * 16 + g * 4 + r;
          T[el * 128 + (s ^ sx)] = f2b(acc[mi][ni][r] + bb);
        }
      }
    __syncthreads();
    int el = tid >> 1, hf = tid & 1;
    int eg = n0 + el, h = eg >> 6, dd = eg & 63;
    int bI = m0 >> 11, sbase = (m0 & 2047) + hf * 64;
    unsigned short* dst = &Vtb[((size_t)(bI * H_ + h) * HD_ + dd) * S_ + sbase];
    const unsigned short* srcR = &T[el * 128];
    int j = el & 15;
    #pragma unroll
    for (int c = 0; c < 8; ++c) {
      int cc = (hf * 8 + c) ^ j;
      uint4 v = *(const uint4*)&srcR[cc * 8];
      *(uint4*)&dst[c * 8] = v;
    }
  } else if (z == 1) {
    // ---- K: write rows directly at compacted position j = rank[s] (skip masked) ----
    #pragma unroll
    for (int mi = 0; mi < 4; ++mi)
      #pragma unroll
      for (int ni = 0; ni < 4; ++ni) {
        int e = n0 + wc * 64 + ni * 16 + l15;
        float bb = bias[e];
        int h = e >> 6, dd = e & 63;
        #pragma unroll
        for (int r = 0; r < 4; ++r) {
          int m = m0 + wr * 64 + mi * 16 + g * 4 + r;
          int b = m >> 11, s = m & 2047;
          int jj = rank[(size_t)b * S_ + s];
          if (jj >= 0) {
            unsigned short u = f2b(acc[mi][ni][r] + bb);
            Kc[((size_t)(b * H_ + h) * S_ + jj) * HD_ + dd] = u;
          }
        }
      }
  } else {
    #pragma unroll
    for (int mi = 0; mi < 4; ++mi)
      #pragma unroll
      for (int ni = 0; ni < 4; ++ni) {
        int e = n0 + wc * 64 + ni * 16 + l15;
        float bb = bias[e];
        int h = e >> 6, dd = e & 63;
        #pragma unroll
        for (int r = 0; r < 4; ++r) {
          int m = m0 + wr * 64 + mi * 16 + g * 4 + r;
          int b = m >> 11, s = m & 2047;
          unsigned short u = f2b((acc[mi][ni][r] + bb) * scale);
          Qb[((size_t)(b * H_ + h) * S_ + s) * HD_ + dd] = u;
        }
      }
  }
}

// ---------------- output projection -> bf16 tmp ----------------
__global__ __launch_bounds__(256) void gemm_proj(const unsigned short* __restrict__ AOb,
    const unsigned short* __restrict__ wob, const float* __restrict__ bo,
    unsigned short* __restrict__ Pfb) {
  __shared__ unsigned short SH[16384];
  int m0 = blockIdx.x * 128, n0 = blockIdx.y * 128;
  f32x4 zero4 = {0.f, 0.f, 0.f, 0.f};
  f32x4 acc[4][4];
  #pragma unroll
  for (int mi = 0; mi < 4; ++mi)
    #pragma unroll
    for (int ni = 0; ni < 4; ++ni) acc[mi][ni] = zero4;
  gemm_core_db32(AOb, wob, m0, n0, acc, SH);
  int tid = threadIdx.x;
  int w = tid >> 6, lane = tid & 63, l15 = lane & 15, g = lane >> 4;
  int wr = w >> 1, wc = w & 1;
  #pragma unroll
  for (int mi = 0; mi < 4; ++mi)
    #pragma unroll
    for (int ni = 0; ni < 4; ++ni) {
      int e = n0 + wc * 64 + ni * 16 + l15;
      float bb = bo[e];
      #pragma unroll
      for (int r = 0; r < 4; ++r) {
        int m = m0 + wr * 64 + mi * 16 + g * 4 + r;
        Pfb[(size_t)m * D_ + e] = f2b(acc[mi][ni][r] + bb);
      }
    }
}

// ---- flash attention over COMPACTED keys: swapped QK^T 32x32x16, in-register P,
// ---- cross-tile pipeline, tail keep-mask (j < nk), XCD-grouped bh assignment.
__global__ __launch_bounds__(256, 2) void attn_kernel(const unsigned short* __restrict__ Qb,
    const unsigned short* __restrict__ Kc, const unsigned short* __restrict__ Vtc,
    const int* __restrict__ nkbuf, unsigned short* __restrict__ AOb) {
  __shared__ unsigned short Ks[3][64 * 64], Vs[3][64 * 64];
  __shared__ uint4 mlds[32][4][2];   // [tile][kp][hi] : keep-mask words for pa
  int bid = blockIdx.y * gridDim.x + blockIdx.x;
  int xcd = bid & 7, jj = bid >> 3;
  int bh = xcd * 4 + (jj >> 4);
  int qblk = jj & 15;
  int b = bh >> 3, h = bh & 7;
  int tid = threadIdx.x, w = tid >> 6, lane = tid & 63;
  int l31 = lane & 31, hi = lane >> 5;
  int q0w = qblk * 128 + w * 32;
  const unsigned short* Qbase = Qb + (size_t)bh * S_ * HD_;
  int nk = nkbuf[b];
  int nt = (nk + 63) >> 6;

  // Q as B-frag (32x32x16); Q is pre-scaled by temp*log2(e)
  bf16x8 qf[4];
  #pragma unroll
  for (int kk = 0; kk < 4; ++kk)
    qf[kk] = *(const bf16x8*)&Qbase[(size_t)(q0w + l31) * HD_ + kk * 16 + hi * 8];

  bf16x8 ones;
  #pragma unroll
  for (int c = 0; c < 8; ++c) ones[c] = (__bf16)1.0f;

  f32x16 out[2], lacc, zc;
  #pragma unroll
  for (int i = 0; i < 16; ++i) { out[0][i] = 0.f; out[1][i] = 0.f; lacc[i] = 0.f; zc[i] = 0.f; }

  f32x16 stA[2], stB[2];

  #define STAGE_KV(buf, kb_) do {                                              \
    _Pragma("unroll")                                                          \
    for (int i = 0; i < 2; ++i) {                                              \
      int l = i * 256 + w * 64 + lane;                                         \
      int row = l >> 3, seg = l & 7;                                           \
      int sseg = seg ^ (row & 7);                                              \
      gload16(Kc + ((size_t)bh * S_ + (kb_) + row) * HD_ + sseg * 8,           \
              (char*)Ks[buf] + (size_t)(i * 256 + w * 64) * 16);               \
      gload16(Vtc + ((size_t)bh * HD_ + row) * S_ + (kb_) + sseg * 8,          \
              (char*)Vs[buf] + (size_t)(i * 256 + w * 64) * 16);               \
    }                                                                          \
  } while (0)

  #define QKT_TILE(KSBUF, ST) do {                                             \
    __builtin_amdgcn_s_setprio(1);                                             \
    const unsigned short* kbase_ = Ks[KSBUF];                                  \
    _Pragma("unroll")                                                          \
    for (int kk = 0; kk < 4; ++kk) {                                           \
      int sw = ((2 * kk + hi) ^ (l31 & 7)) * 8;                                \
      bf16x8 ka0 = *(const bf16x8*)&kbase_[l31 * 64 + sw];                     \
      bf16x8 ka1 = *(const bf16x8*)&kbase_[(32 + l31) * 64 + sw];              \
      ST[0] = __builtin_amdgcn_mfma_f32_32x32x16_bf16(ka0, qf[kk], kk ? ST[0] : zc, 0, 0, 0); \
      ST[1] = __builtin_amdgcn_mfma_f32_32x32x16_bf16(ka1, qf[kk], kk ? ST[1] : zc, 0, 0, 0); \
    }                                                                          \
    __builtin_amdgcn_s_setprio(0);                                             \
  } while (0)

  // BODY(T): barrier; stage T+2; QKT(T+1)->STN; exp2(STC); PV(T) with packed-AND masking.
  #define TILE_BODY(T, STC, STN, bPV, bQK, bST) do {                           \
    __syncthreads();                                                           \
    if ((T) + 2 < nt) STAGE_KV(bST, ((T) + 2) * 64);                           \
    if ((T) + 1 < nt) QKT_TILE(bQK, STN);                                      \
    _Pragma("unroll")                                                          \
    for (int ktile = 0; ktile < 2; ++ktile)                                    \
      _Pragma("unroll")                                                        \
      for (int reg = 0; reg < 16; ++reg)                                       \
        STC[ktile][reg] = exp2_hw(STC[ktile][reg]);                            \
    __builtin_amdgcn_s_setprio(1);                                             \
    const unsigned short* vbase_ = Vs[bPV];                                    \
    _Pragma("unroll")                                                          \
    for (int kp = 0; kp < 4; ++kp) {                                           \
      const int kt8 = kp >> 1;                                                 \
      const int ro = 8 * (kp & 1);                                             \
      uint4 mw = mlds[(T)][kp][hi];                                            \
      unsigned Xa = cvtpk_bf16(STC[kt8][ro + 0], STC[kt8][ro + 1]);            \
      unsigned Ya = cvtpk_bf16(STC[kt8][ro + 4], STC[kt8][ro + 5]);            \
      unsigned Xb = cvtpk_bf16(STC[kt8][ro + 2], STC[kt8][ro + 3]);            \
      unsigned Yb = cvtpk_bf16(STC[kt8][ro + 6], STC[kt8][ro + 7]);            \
      plswap(Xa, Ya);                                                          \
      plswap(Xb, Yb);                                                          \
      union { unsigned u[4]; bf16x8 v; } pu;                                   \
      pu.u[0] = Xa & mw.x; pu.u[1] = Xb & mw.y;                                \
      pu.u[2] = Ya & mw.z; pu.u[3] = Yb & mw.w;                                \
      bf16x8 pa = pu.v;                                                        \
      _Pragma("unroll")                                                        \
      for (int dn = 0; dn < 2; ++dn) {                                         \
        int row = dn * 32 + l31;                                               \
        bf16x8 vb = *(const bf16x8*)&vbase_[row * 64 + ((2 * kp + hi) ^ (row & 7)) * 8]; \
        out[dn] = __builtin_amdgcn_mfma_f32_32x32x16_bf16(pa, vb, out[dn], 0, 0, 0); \
      }                                                                        \
      lacc = __builtin_amdgcn_mfma_f32_32x32x16_bf16(pa, ones, lacc, 0, 0, 0); \
    }                                                                          \
    __builtin_amdgcn_s_setprio(0);                                             \
  } while (0)

  // ---- prologue: stage 0,1; build tail keep-mask table (keep iff key j < nk); QKT(0) ----
  STAGE_KV(0, 0);
  {
    int t = tid;
    int tile = t >> 3, kp = (t >> 1) & 3, hh = t & 1;
    int j0 = tile * 64 + kp * 16 + hh * 8;
    uint4 mw;
    mw.x = ((j0 + 0 < nk) ? 0x0000FFFFu : 0u) | ((j0 + 1 < nk) ? 0xFFFF0000u : 0u);
    mw.y = ((j0 + 2 < nk) ? 0x0000FFFFu : 0u) | ((j0 + 3 < nk) ? 0xFFFF0000u : 0u);
    mw.z = ((j0 + 4 < nk) ? 0x0000FFFFu : 0u) | ((j0 + 5 < nk) ? 0xFFFF0000u : 0u);
    mw.w = ((j0 + 6 < nk) ? 0x0000FFFFu : 0u) | ((j0 + 7 < nk) ? 0xFFFF0000u : 0u);
    mlds[tile][kp][hh] = mw;
  }
  __syncthreads();
  if (nt > 1) STAGE_KV(1, 64);
  QKT_TILE(0, stA);

  int t = 0;
  for (; t + 1 < nt; t += 2) {
    TILE_BODY(t, stA, stB, t % 3, (t + 1) % 3, (t + 2) % 3);
    TILE_BODY(t + 1, stB, stA, (t + 1) % 3, (t + 2) % 3, t % 3);
  }
  if (t < nt) TILE_BODY(t, stA, stB, t % 3, (t + 1) % 3, (t + 2) % 3);

  // ---- epilogue: out[q = q0w + crow][d = dn*32 + l31] / lsum[q] ----
  #pragma unroll
  for (int reg = 0; reg < 16; ++reg) {
    float inv = 1.f / lacc[reg];
    int q = q0w + (reg & 3) + 8 * (reg >> 2) + 4 * hi;
    #pragma unroll
    for (int dn = 0; dn < 2; ++dn)
      AOb[((size_t)b * S_ + q) * D_ + h * HD_ + dn * 32 + l31] = f2b(out[dn][reg] * inv);
  }
  #undef TILE_BODY
  #undef QKT_TILE
  #undef STAGE_KV
}

// ---------------- residual + LayerNorm (proj tmp in bf16) ----------------
__global__ __launch_bounds__(256) void ln_kernel(const unsigned short* __restrict__ Pfb,
    const float* __restrict__ x, const float* __restrict__ gamma,
    const float* __restrict__ beta, float* __restrict__ out) {
  int row = blockIdx.x * 4 + (threadIdx.x >> 6);
  int lane = threadIdx.x & 63;
  const unsigned short* pr = Pfb + (size_t)row * D_;
  const float* xr = x + (size_t)row * D_;
  ushort4 p0 = *(const ushort4*)(pr + lane * 8);
  ushort4 p1 = *(const ushort4*)(pr + lane * 8 + 4);
  float4 b0 = *(const float4*)(xr + lane * 8);
  float4 b1 = *(const float4*)(xr + lane * 8 + 4);
  float y[8] = {b2f(p0.x) + b0.x, b2f(p0.y) + b0.y, b2f(p0.z) + b0.z, b2f(p0.w) + b0.w,
                b2f(p1.x) + b1.x, b2f(p1.y) + b1.y, b2f(p1.z) + b1.z, b2f(p1.w) + b1.w};
  float s = 0.f, s2 = 0.f;
  #pragma unroll
  for (int i = 0; i < 8; ++i) { s += y[i]; s2 += y[i] * y[i]; }
  #pragma unroll
  for (int d = 1; d < 64; d <<= 1) { s += __shfl_xor(s, d); s2 += __shfl_xor(s2, d); }
  float mu = s * (1.f / 512.f);
  float var = s2 * (1.f / 512.f) - mu * mu;
  float inv = rsqrtf(fmaxf(var, 0.f) + 1e-6f);
  float4 g0 = *(const float4*)(gamma + lane * 8);
  float4 g1 = *(const float4*)(gamma + lane * 8 + 4);
  float4 e0 = *(const float4*)(beta + lane * 8);
  float4 e1 = *(const float4*)(beta + lane * 8 + 4);
  float* orow = out + (size_t)row * D_;
  float4 o0 = {(y[0] - mu) * inv * g0.x + e0.x, (y[1] - mu) * inv * g0.y + e0.y,
               (y[2] - mu) * inv * g0.z + e0.z, (y[3] - mu) * inv * g0.w + e0.w};
  float4 o1 = {(y[4] - mu) * inv * g1.x + e1.x, (y[5] - mu) * inv * g1.y + e1.y,
               (y[6] - mu) * inv * g1.z + e1.z, (y[7] - mu) * inv * g1.w + e1.w};
  *(float4*)(orow + lane * 8) = o0;
  *(float4*)(orow + lane * 8 + 4) = o1;
}

extern "C" void kernel_launch(void* const* d_in, const int* in_sizes, int n_in,
                              void* d_out, int out_size, void* d_ws, size_t ws_size,
                              hipStream_t stream) {
  const float* x = (const float*)d_in[0];
  const int* mask = (const int*)d_in[1];
  const float* wq = (const float*)d_in[2];
  const float* bq = (const float*)d_in[3];
  const float* wk = (const float*)d_in[4];
  const float* bk = (const float*)d_in[5];
  const float* wv = (const float*)d_in[6];
  const float* bv = (const float*)d_in[7];
  const float* wo = (const float*)d_in[8];
  const float* bo = (const float*)d_in[9];
  const float* gamma = (const float*)d_in[10];
  const float* beta = (const float*)d_in[11];
  const float* temp = (const float*)d_in[12];
  float* out = (float*)d_out;
  char* ws = (char*)d_ws;
  const size_t MB = (size_t)1 << 20;
  unsigned short* xb  = (unsigned short*)(ws);                    // 8 MB
  unsigned short* wqb = (unsigned short*)(ws + 8 * MB);           // 0.5 MB
  unsigned short* wkb = (unsigned short*)(ws + 8 * MB + 512 * 1024);
  unsigned short* wvb = (unsigned short*)(ws + 9 * MB);
  unsigned short* wob = (unsigned short*)(ws + 9 * MB + 512 * 1024);
  unsigned short* Qb  = (unsigned short*)(ws + 10 * MB);          // 8 MB
  unsigned short* Pfb = (unsigned short*)(ws + 18 * MB);          // 8 MB bf16
  unsigned short* Vtb = (unsigned short*)(ws + 26 * MB);          // 8 MB
  unsigned short* AOb = (unsigned short*)(ws + 34 * MB);          // 8 MB
  unsigned short* Kc  = (unsigned short*)(ws + 42 * MB);          // 8 MB compacted K
  unsigned short* Vtc = (unsigned short*)(ws + 50 * MB);          // 8 MB compacted Vt
  int*            idx = (int*)(ws + 58 * MB);                     // 32 KB
  int*            rnk = (int*)(ws + 58 * MB + 64 * 1024);         // 32 KB
  int*            nkb = (int*)(ws + 58 * MB + 128 * 1024);        // 16 B

  cvt_all_kernel<<<(XN4 + 4 * WN4 + 255) / 256, 256, 0, stream>>>(
      x, wq, wk, wv, wo, xb, wqb, wkb, wvb, wob);
  rank_kernel<<<4, 64, 0, stream>>>(mask, idx, rnk, nkb);
  gemm_qkv<<<dim3(64, 4, 3), 256, 0, stream>>>(xb, wqb, wkb, wvb, bq, bk, bv, temp, rnk, Qb, Kc, Vtb);
  compact_kernel<<<dim3(64, 32), 256, 0, stream>>>(Vtb, idx, nkb, Vtc);
  attn_kernel<<<dim3(16, 32), 256, 0, stream>>>(Qb, Kc, Vtc, nkb, AOb);
  gemm_proj<<<dim3(64, 4), 256, 0, stream>>>(AOb, wob, bo, Pfb);
  ln_kernel<<<2048, 256, 0, stream>>>(Pfb, x, gamma, beta, out);
}

// Round 21
// 98.796 us; speedup vs baseline: 1.1742x; 1.0197x over previous
//
#include <hip/hip_runtime.h>
#include <hip/hip_bf16.h>
#include <stdint.h>

#define B_ 4
#define S_ 2048
#define D_ 512
#define H_ 8
#define HD_ 64
#define M_ (B_*S_)   // 8192

typedef __bf16 bf16x8 __attribute__((ext_vector_type(8)));
typedef float f32x4 __attribute__((ext_vector_type(4)));
typedef float f32x16 __attribute__((ext_vector_type(16)));

__device__ __forceinline__ unsigned short f2b(float f) {
  union { float f; unsigned u; } v; v.f = f;
  unsigned r = v.u + 0x7fff + ((v.u >> 16) & 1);
  return (unsigned short)(r >> 16);
}

__device__ __forceinline__ float b2f(unsigned short u) {
  union { unsigned u; float f; } v; v.u = (unsigned)u << 16;
  return v.f;
}

__device__ __forceinline__ float exp2_hw(float x) {
  return __builtin_amdgcn_exp2f(x);  // v_exp_f32: D = 2^S0
}

__device__ __forceinline__ unsigned cvtpk_bf16(float lo, float hi) {
  unsigned r;
  asm("v_cvt_pk_bf16_f32 %0, %1, %2" : "=v"(r) : "v"(lo), "v"(hi));
  return r;
}

__device__ __forceinline__ void plswap(unsigned &a, unsigned &b) {
  asm volatile("v_permlane32_swap_b32 %0, %1" : "+v"(a), "+v"(b));
}

__device__ __forceinline__ void gload16(const void* g, void* lds) {
  __builtin_amdgcn_global_load_lds(
      (const __attribute__((address_space(1))) unsigned int*)g,
      (__attribute__((address_space(3))) unsigned int*)lds, 16, 0, 0);
}

// ---------------- f32 -> bf16 conversion (x + all 4 weights, one launch) ----------------
#define XN4 (M_ * D_ / 4)
#define WN4 (D_ * D_ / 4)
__global__ __launch_bounds__(256) void cvt_all_kernel(const float* __restrict__ x,
    const float* __restrict__ wq, const float* __restrict__ wk,
    const float* __restrict__ wv, const float* __restrict__ wo,
    unsigned short* __restrict__ xb, unsigned short* __restrict__ wqb,
    unsigned short* __restrict__ wkb, unsigned short* __restrict__ wvb,
    unsigned short* __restrict__ wob) {
  int i = blockIdx.x * blockDim.x + threadIdx.x;
  const float* src; unsigned short* dst; int off;
  if (i < XN4) { src = x; dst = xb; off = i; }
  else {
    int j = i - XN4;
    int sel = j / WN4; off = j - sel * WN4;
    src = (sel == 0) ? wq : (sel == 1) ? wk : (sel == 2) ? wv : wo;
    dst = (sel == 0) ? wqb : (sel == 1) ? wkb : (sel == 2) ? wvb : wob;
  }
  float4 v = ((const float4*)src)[off];
  ushort4 o;
  o.x = f2b(v.x); o.y = f2b(v.y); o.z = f2b(v.z); o.w = f2b(v.w);
  ((ushort4*)dst)[off] = o;
}

// ---------------- mask rank/index precompute: 1 wave per batch ----------------
__global__ __launch_bounds__(64) void rank_kernel(const int* __restrict__ mask,
    int* __restrict__ idx, int* __restrict__ rank, int* __restrict__ nkbuf) {
  int b = blockIdx.x, lane = threadIdx.x;
  const int* mb = mask + (size_t)b * S_;
  int base = 0;
  for (int c = 0; c < 32; ++c) {
    int s = c * 64 + lane;
    int m = mb[s];
    unsigned long long keep = __ballot(m == 0);
    int my = base + __popcll(keep & ((1ull << lane) - 1ull));
    if (m == 0) idx[(size_t)b * S_ + my] = s;    // j -> s
    rank[(size_t)b * S_ + s] = (m == 0) ? my : -1;  // s -> j
    base += __popcll(keep);
  }
  if (lane == 0) nkbuf[b] = base;
}

// ---------------- compact Vt (columns) by idx ----------------
__global__ __launch_bounds__(256) void compact_kernel(
    const unsigned short* __restrict__ Vtb, const int* __restrict__ idx,
    const int* __restrict__ nkbuf, unsigned short* __restrict__ Vtc) {
  int bh = blockIdx.y, b = bh >> 3;
  int nk = nkbuf[b];
  const int* ib = idx + (size_t)b * S_;
  int tid = threadIdx.x;
  int d = blockIdx.x;
  const unsigned short* src = &Vtb[((size_t)bh * HD_ + d) * S_];
  unsigned short* dst = &Vtc[((size_t)bh * HD_ + d) * S_];
  int j0 = tid * 8;
  if (j0 < nk) {
    unsigned short tmp[8];
    #pragma unroll
    for (int c = 0; c < 8; ++c) {
      int j = j0 + c;
      tmp[c] = (j < nk) ? src[ib[j]] : (unsigned short)0;
    }
    *(uint4*)&dst[j0] = *(uint4*)tmp;
  }
}

// ------- GEMM core, double-buffered BK=64 (for gemm_proj) -------
__device__ __forceinline__ void gemm_core_db(const unsigned short* __restrict__ A,
                                             const unsigned short* __restrict__ W,
                                             int m0, int n0, f32x4 (&acc)[4][4],
                                             unsigned short (&As)[2][128 * 64],
                                             unsigned short (&Bs)[2][128 * 64]) {
  int tid = threadIdx.x;
  int w = tid >> 6, lane = tid & 63;
  int l15 = lane & 15, g = lane >> 4;
  int wr = w >> 1, wc = w & 1;
  #define STAGE_G(buf, k0_) do {                                               \
    _Pragma("unroll")                                                          \
    for (int i = 0; i < 4; ++i) {                                              \
      int l = i * 256 + w * 64 + lane;                                         \
      int row = l >> 3, seg = l & 7;                                           \
      int sseg = seg ^ (row & 7);                                              \
      gload16(A + (size_t)(m0 + row) * D_ + (k0_) + sseg * 8,                  \
              (char*)As[buf] + (size_t)(i * 256 + w * 64) * 16);               \
      gload16(W + (size_t)(n0 + row) * D_ + (k0_) + sseg * 8,                  \
              (char*)Bs[buf] + (size_t)(i * 256 + w * 64) * 16);               \
    }                                                                          \
  } while (0)
  STAGE_G(0, 0);
  __syncthreads();
  for (int ks = 0; ks < 8; ++ks) {
    int cur = ks & 1;
    if (ks < 7) STAGE_G(cur ^ 1, (ks + 1) * 64);
    #pragma unroll
    for (int kk = 0; kk < 2; ++kk) {
      int sw = ((kk * 4 + g) ^ (l15 & 7)) * 8;
      bf16x8 af[4], bfr[4];
      #pragma unroll
      for (int t = 0; t < 4; ++t) {
        af[t]  = *(const bf16x8*)&As[cur][(wr * 64 + t * 16 + l15) * 64 + sw];
        bfr[t] = *(const bf16x8*)&Bs[cur][(wc * 64 + t * 16 + l15) * 64 + sw];
      }
      #pragma unroll
      for (int mi = 0; mi < 4; ++mi)
        #pragma unroll
        for (int ni = 0; ni < 4; ++ni)
          acc[mi][ni] = __builtin_amdgcn_mfma_f32_16x16x32_bf16(af[mi], bfr[ni], acc[mi][ni], 0, 0, 0);
    }
    __syncthreads();
  }
  #undef STAGE_G
}

// ------- GEMM core, double-buffered BK=32 (for gemm_qkv: higher occupancy) -------
// SH layout (shorts): A bufs at 0 / 4096, B bufs at 8192 / 12288 (total 16384 = 32 KB).
__device__ __forceinline__ void gemm_core_db32(const unsigned short* __restrict__ A,
                                               const unsigned short* __restrict__ W,
                                               int m0, int n0, f32x4 (&acc)[4][4],
                                               unsigned short* SH) {
  int tid = threadIdx.x;
  int w = tid >> 6, lane = tid & 63;
  int l15 = lane & 15, g = lane >> 4;
  int wr = w >> 1, wc = w & 1;
  #define STAGE32(ab, buf, P, r0_, k0_) do {                                   \
    _Pragma("unroll")                                                          \
    for (int i = 0; i < 2; ++i) {                                              \
      int l = i * 256 + tid;                                                   \
      int row = l >> 2, seg = l & 3;                                           \
      int sseg = seg ^ (row & 3);                                              \
      gload16((P) + (size_t)((r0_) + row) * D_ + (k0_) + sseg * 8,             \
              (char*)(SH + (ab) * 8192 + (buf) * 4096) + (size_t)l * 16);      \
    }                                                                          \
  } while (0)
  STAGE32(0, 0, A, m0, 0);
  STAGE32(1, 0, W, n0, 0);
  __syncthreads();
  for (int ks = 0; ks < 16; ++ks) {
    int cur = ks & 1;
    if (ks < 15) {
      STAGE32(0, cur ^ 1, A, m0, (ks + 1) * 32);
      STAGE32(1, cur ^ 1, W, n0, (ks + 1) * 32);
    }
    bf16x8 af[4], bfr[4];
    #pragma unroll
    for (int t = 0; t < 4; ++t) {
      int ra = wr * 64 + t * 16 + l15;
      af[t]  = *(const bf16x8*)&SH[cur * 4096 + ra * 32 + ((g ^ (ra & 3)) * 8)];
      int rb = wc * 64 + t * 16 + l15;
      bfr[t] = *(const bf16x8*)&SH[8192 + cur * 4096 + rb * 32 + ((g ^ (rb & 3)) * 8)];
    }
    #pragma unroll
    for (int mi = 0; mi < 4; ++mi)
      #pragma unroll
      for (int ni = 0; ni < 4; ++ni)
        acc[mi][ni] = __builtin_amdgcn_mfma_f32_16x16x32_bf16(af[mi], bfr[ni], acc[mi][ni], 0, 0, 0);
    __syncthreads();
  }
  #undef STAGE32
}

// ---- QKV projection, grid (64,4,3); Q pre-scaled; K written compacted via rank; V via LDS ----
__global__ __launch_bounds__(256) void gemm_qkv(const unsigned short* __restrict__ xb,
    const unsigned short* __restrict__ wqb, const unsigned short* __restrict__ wkb,
    const unsigned short* __restrict__ wvb,
    const float* __restrict__ bq, const float* __restrict__ bk, const float* __restrict__ bv,
    const float* __restrict__ tptr, const int* __restrict__ rank,
    unsigned short* __restrict__ Qb, unsigned short* __restrict__ Kc, unsigned short* __restrict__ Vtb) {
  __shared__ unsigned short SH[16384];   // 32 KB: GEMM bufs; reused as V-transpose scratch
  int z = blockIdx.z;
  const unsigned short* W = (z == 0) ? wqb : ((z == 1) ? wkb : wvb);
  const float* bias = (z == 0) ? bq : ((z == 1) ? bk : bv);
  float scale = (z == 0) ? tptr[0] * 1.44269504088896340736f : 1.0f;
  int m0 = blockIdx.x * 128, n0 = blockIdx.y * 128;
  f32x4 zero4 = {0.f, 0.f, 0.f, 0.f};
  f32x4 acc[4][4];
  #pragma unroll
  for (int mi = 0; mi < 4; ++mi)
    #pragma unroll
    for (int ni = 0; ni < 4; ++ni) acc[mi][ni] = zero4;
  gemm_core_db32(xb, W, m0, n0, acc, SH);
  int tid = threadIdx.x;
  int w = tid >> 6, lane = tid & 63, l15 = lane & 15, g = lane >> 4;
  int wr = w >> 1, wc = w & 1;
  if (z == 2) {
    // ---- V: acc -> LDS T[e][s ^ ((e&15)<<3)] bf16 (T = SH, [128][128]), coalesced store ----
    unsigned short* T = SH;
    #pragma unroll
    for (int mi = 0; mi < 4; ++mi)
      #pragma unroll
      for (int ni = 0; ni < 4; ++ni) {
        int el = wc * 64 + ni * 16 + l15;
        float bb = bias[n0 + el];
        int sx = (el & 15) << 3;
        #pragma unroll
        for (int r = 0; r < 4; ++r) {
          int s = wr * 64 + mi * 16 + g * 4 + r;
          T[el * 128 + (s ^ sx)] = f2b(acc[mi][ni][r] + bb);
        }
      }
    __syncthreads();
    int el = tid >> 1, hf = tid & 1;
    int eg = n0 + el, h = eg >> 6, dd = eg & 63;
    int bI = m0 >> 11, sbase = (m0 & 2047) + hf * 64;
    unsigned short* dst = &Vtb[((size_t)(bI * H_ + h) * HD_ + dd) * S_ + sbase];
    const unsigned short* srcR = &T[el * 128];
    int j = el & 15;
    #pragma unroll
    for (int c = 0; c < 8; ++c) {
      int cc = (hf * 8 + c) ^ j;
      uint4 v = *(const uint4*)&srcR[cc * 8];
      *(uint4*)&dst[c * 8] = v;
    }
  } else if (z == 1) {
    // ---- K: write rows directly at compacted position j = rank[s] (skip masked) ----
    #pragma unroll
    for (int mi = 0; mi < 4; ++mi)
      #pragma unroll
      for (int ni = 0; ni < 4; ++ni) {
        int e = n0 + wc * 64 + ni * 16 + l15;
        float bb = bias[e];
        int h = e >> 6, dd = e & 63;
        #pragma unroll
        for (int r = 0; r < 4; ++r) {
          int m = m0 + wr * 64 + mi * 16 + g * 4 + r;
          int b = m >> 11, s = m & 2047;
          int jj = rank[(size_t)b * S_ + s];
          if (jj >= 0) {
            unsigned short u = f2b(acc[mi][ni][r] + bb);
            Kc[((size_t)(b * H_ + h) * S_ + jj) * HD_ + dd] = u;
          }
        }
      }
  } else {
    #pragma unroll
    for (int mi = 0; mi < 4; ++mi)
      #pragma unroll
      for (int ni = 0; ni < 4; ++ni) {
        int e = n0 + wc * 64 + ni * 16 + l15;
        float bb = bias[e];
        int h = e >> 6, dd = e & 63;
        #pragma unroll
        for (int r = 0; r < 4; ++r) {
          int m = m0 + wr * 64 + mi * 16 + g * 4 + r;
          int b = m >> 11, s = m & 2047;
          unsigned short u = f2b((acc[mi][ni][r] + bb) * scale);
          Qb[((size_t)(b * H_ + h) * S_ + s) * HD_ + dd] = u;
        }
      }
  }
}

// ---------------- output projection -> bf16 tmp (BK=64 core) ----------------
__global__ __launch_bounds__(256) void gemm_proj(const unsigned short* __restrict__ AOb,
    const unsigned short* __restrict__ wob, const float* __restrict__ bo,
    unsigned short* __restrict__ Pfb) {
  __shared__ unsigned short As[2][128 * 64], Bs[2][128 * 64];
  int m0 = blockIdx.x * 128, n0 = blockIdx.y * 128;
  f32x4 zero4 = {0.f, 0.f, 0.f, 0.f};
  f32x4 acc[4][4];
  #pragma unroll
  for (int mi = 0; mi < 4; ++mi)
    #pragma unroll
    for (int ni = 0; ni < 4; ++ni) acc[mi][ni] = zero4;
  gemm_core_db(AOb, wob, m0, n0, acc, As, Bs);
  int tid = threadIdx.x;
  int w = tid >> 6, lane = tid & 63, l15 = lane & 15, g = lane >> 4;
  int wr = w >> 1, wc = w & 1;
  #pragma unroll
  for (int mi = 0; mi < 4; ++mi)
    #pragma unroll
    for (int ni = 0; ni < 4; ++ni) {
      int e = n0 + wc * 64 + ni * 16 + l15;
      float bb = bo[e];
      #pragma unroll
      for (int r = 0; r < 4; ++r) {
        int m = m0 + wr * 64 + mi * 16 + g * 4 + r;
        Pfb[(size_t)m * D_ + e] = f2b(acc[mi][ni][r] + bb);
      }
    }
}

// ---- flash attention over COMPACTED keys: swapped QK^T 32x32x16, in-register P,
// ---- cross-tile pipeline, tail keep-mask (j < nk), XCD-grouped bh assignment.
__global__ __launch_bounds__(256, 2) void attn_kernel(const unsigned short* __restrict__ Qb,
    const unsigned short* __restrict__ Kc, const unsigned short* __restrict__ Vtc,
    const int* __restrict__ nkbuf, unsigned short* __restrict__ AOb) {
  __shared__ unsigned short Ks[3][64 * 64], Vs[3][64 * 64];
  __shared__ uint4 mlds[32][4][2];   // [tile][kp][hi] : keep-mask words for pa
  int bid = blockIdx.y * gridDim.x + blockIdx.x;
  int xcd = bid & 7, jj = bid >> 3;
  int bh = xcd * 4 + (jj >> 4);
  int qblk = jj & 15;
  int b = bh >> 3, h = bh & 7;
  int tid = threadIdx.x, w = tid >> 6, lane = tid & 63;
  int l31 = lane & 31, hi = lane >> 5;
  int q0w = qblk * 128 + w * 32;
  const unsigned short* Qbase = Qb + (size_t)bh * S_ * HD_;
  int nk = nkbuf[b];
  int nt = (nk + 63) >> 6;

  // Q as B-frag (32x32x16); Q is pre-scaled by temp*log2(e)
  bf16x8 qf[4];
  #pragma unroll
  for (int kk = 0; kk < 4; ++kk)
    qf[kk] = *(const bf16x8*)&Qbase[(size_t)(q0w + l31) * HD_ + kk * 16 + hi * 8];

  bf16x8 ones;
  #pragma unroll
  for (int c = 0; c < 8; ++c) ones[c] = (__bf16)1.0f;

  f32x16 out[2], lacc, zc;
  #pragma unroll
  for (int i = 0; i < 16; ++i) { out[0][i] = 0.f; out[1][i] = 0.f; lacc[i] = 0.f; zc[i] = 0.f; }

  f32x16 stA[2], stB[2];

  #define STAGE_KV(buf, kb_) do {                                              \
    _Pragma("unroll")                                                          \
    for (int i = 0; i < 2; ++i) {                                              \
      int l = i * 256 + w * 64 + lane;                                         \
      int row = l >> 3, seg = l & 7;                                           \
      int sseg = seg ^ (row & 7);                                              \
      gload16(Kc + ((size_t)bh * S_ + (kb_) + row) * HD_ + sseg * 8,           \
              (char*)Ks[buf] + (size_t)(i * 256 + w * 64) * 16);               \
      gload16(Vtc + ((size_t)bh * HD_ + row) * S_ + (kb_) + sseg * 8,          \
              (char*)Vs[buf] + (size_t)(i * 256 + w * 64) * 16);               \
    }                                                                          \
  } while (0)

  #define QKT_TILE(KSBUF, ST) do {                                             \
    __builtin_amdgcn_s_setprio(1);                                             \
    const unsigned short* kbase_ = Ks[KSBUF];                                  \
    _Pragma("unroll")                                                          \
    for (int kk = 0; kk < 4; ++kk) {                                           \
      int sw = ((2 * kk + hi) ^ (l31 & 7)) * 8;                                \
      bf16x8 ka0 = *(const bf16x8*)&kbase_[l31 * 64 + sw];                     \
      bf16x8 ka1 = *(const bf16x8*)&kbase_[(32 + l31) * 64 + sw];              \
      ST[0] = __builtin_amdgcn_mfma_f32_32x32x16_bf16(ka0, qf[kk], kk ? ST[0] : zc, 0, 0, 0); \
      ST[1] = __builtin_amdgcn_mfma_f32_32x32x16_bf16(ka1, qf[kk], kk ? ST[1] : zc, 0, 0, 0); \
    }                                                                          \
    __builtin_amdgcn_s_setprio(0);                                             \
  } while (0)

  // BODY(T): barrier; stage T+2; QKT(T+1)->STN; exp2(STC); PV(T) with packed-AND masking.
  #define TILE_BODY(T, STC, STN, bPV, bQK, bST) do {                           \
    __syncthreads();                                                           \
    if ((T) + 2 < nt) STAGE_KV(bST, ((T) + 2) * 64);                           \
    if ((T) + 1 < nt) QKT_TILE(bQK, STN);                                      \
    _Pragma("unroll")                                                          \
    for (int ktile = 0; ktile < 2; ++ktile)                                    \
      _Pragma("unroll")                                                        \
      for (int reg = 0; reg < 16; ++reg)                                       \
        STC[ktile][reg] = exp2_hw(STC[ktile][reg]);                            \
    __builtin_amdgcn_s_setprio(1);                                             \
    const unsigned short* vbase_ = Vs[bPV];                                    \
    _Pragma("unroll")                                                          \
    for (int kp = 0; kp < 4; ++kp) {                                           \
      const int kt8 = kp >> 1;                                                 \
      const int ro = 8 * (kp & 1);                                             \
      uint4 mw = mlds[(T)][kp][hi];                                            \
      unsigned Xa = cvtpk_bf16(STC[kt8][ro + 0], STC[kt8][ro + 1]);            \
      unsigned Ya = cvtpk_bf16(STC[kt8][ro + 4], STC[kt8][ro + 5]);            \
      unsigned Xb = cvtpk_bf16(STC[kt8][ro + 2], STC[kt8][ro + 3]);            \
      unsigned Yb = cvtpk_bf16(STC[kt8][ro + 6], STC[kt8][ro + 7]);            \
      plswap(Xa, Ya);                                                          \
      plswap(Xb, Yb);                                                          \
      union { unsigned u[4]; bf16x8 v; } pu;                                   \
      pu.u[0] = Xa & mw.x; pu.u[1] = Xb & mw.y;                                \
      pu.u[2] = Ya & mw.z; pu.u[3] = Yb & mw.w;                                \
      bf16x8 pa = pu.v;                                                        \
      _Pragma("unroll")                                                        \
      for (int dn = 0; dn < 2; ++dn) {                                         \
        int row = dn * 32 + l31;                                               \
        bf16x8 vb = *(const bf16x8*)&vbase_[row * 64 + ((2 * kp + hi) ^ (row & 7)) * 8]; \
        out[dn] = __builtin_amdgcn_mfma_f32_32x32x16_bf16(pa, vb, out[dn], 0, 0, 0); \
      }                                                                        \
      lacc = __builtin_amdgcn_mfma_f32_32x32x16_bf16(pa, ones, lacc, 0, 0, 0); \
    }                                                                          \
    __builtin_amdgcn_s_setprio(0);                                             \
  } while (0)

  // ---- prologue: stage 0,1; build tail keep-mask table (keep iff key j < nk); QKT(0) ----
  STAGE_KV(0, 0);
  {
    int t = tid;
    int tile = t >> 3, kp = (t >> 1) & 3, hh = t & 1;
    int j0 = tile * 64 + kp * 16 + hh * 8;
    uint4 mw;
    mw.x = ((j0 + 0 < nk) ? 0x0000FFFFu : 0u) | ((j0 + 1 < nk) ? 0xFFFF0000u : 0u);
    mw.y = ((j0 + 2 < nk) ? 0x0000FFFFu : 0u) | ((j0 + 3 < nk) ? 0xFFFF0000u : 0u);
    mw.z = ((j0 + 4 < nk) ? 0x0000FFFFu : 0u) | ((j0 + 5 < nk) ? 0xFFFF0000u : 0u);
    mw.w = ((j0 + 6 < nk) ? 0x0000FFFFu : 0u) | ((j0 + 7 < nk) ? 0xFFFF0000u : 0u);
    mlds[tile][kp][hh] = mw;
  }
  __syncthreads();
  if (nt > 1) STAGE_KV(1, 64);
  QKT_TILE(0, stA);

  int t = 0;
  for (; t + 1 < nt; t += 2) {
    TILE_BODY(t, stA, stB, t % 3, (t + 1) % 3, (t + 2) % 3);
    TILE_BODY(t + 1, stB, stA, (t + 1) % 3, (t + 2) % 3, t % 3);
  }
  if (t < nt) TILE_BODY(t, stA, stB, t % 3, (t + 1) % 3, (t + 2) % 3);

  // ---- epilogue: out[q = q0w + crow][d = dn*32 + l31] / lsum[q] ----
  #pragma unroll
  for (int reg = 0; reg < 16; ++reg) {
    float inv = 1.f / lacc[reg];
    int q = q0w + (reg & 3) + 8 * (reg >> 2) + 4 * hi;
    #pragma unroll
    for (int dn = 0; dn < 2; ++dn)
      AOb[((size_t)b * S_ + q) * D_ + h * HD_ + dn * 32 + l31] = f2b(out[dn][reg] * inv);
  }
  #undef TILE_BODY
  #undef QKT_TILE
  #undef STAGE_KV
}

// ---------------- residual + LayerNorm (proj tmp in bf16) ----------------
__global__ __launch_bounds__(256) void ln_kernel(const unsigned short* __restrict__ Pfb,
    const float* __restrict__ x, const float* __restrict__ gamma,
    const float* __restrict__ beta, float* __restrict__ out) {
  int row = blockIdx.x * 4 + (threadIdx.x >> 6);
  int lane = threadIdx.x & 63;
  const unsigned short* pr = Pfb + (size_t)row * D_;
  const float* xr = x + (size_t)row * D_;
  ushort4 p0 = *(const ushort4*)(pr + lane * 8);
  ushort4 p1 = *(const ushort4*)(pr + lane * 8 + 4);
  float4 b0 = *(const float4*)(xr + lane * 8);
  float4 b1 = *(const float4*)(xr + lane * 8 + 4);
  float y[8] = {b2f(p0.x) + b0.x, b2f(p0.y) + b0.y, b2f(p0.z) + b0.z, b2f(p0.w) + b0.w,
                b2f(p1.x) + b1.x, b2f(p1.y) + b1.y, b2f(p1.z) + b1.z, b2f(p1.w) + b1.w};
  float s = 0.f, s2 = 0.f;
  #pragma unroll
  for (int i = 0; i < 8; ++i) { s += y[i]; s2 += y[i] * y[i]; }
  #pragma unroll
  for (int d = 1; d < 64; d <<= 1) { s += __shfl_xor(s, d); s2 += __shfl_xor(s2, d); }
  float mu = s * (1.f / 512.f);
  float var = s2 * (1.f / 512.f) - mu * mu;
  float inv = rsqrtf(fmaxf(var, 0.f) + 1e-6f);
  float4 g0 = *(const float4*)(gamma + lane * 8);
  float4 g1 = *(const float4*)(gamma + lane * 8 + 4);
  float4 e0 = *(const float4*)(beta + lane * 8);
  float4 e1 = *(const float4*)(beta + lane * 8 + 4);
  float* orow = out + (size_t)row * D_;
  float4 o0 = {(y[0] - mu) * inv * g0.x + e0.x, (y[1] - mu) * inv * g0.y + e0.y,
               (y[2] - mu) * inv * g0.z + e0.z, (y[3] - mu) * inv * g0.w + e0.w};
  float4 o1 = {(y[4] - mu) * inv * g1.x + e1.x, (y[5] - mu) * inv * g1.y + e1.y,
               (y[6] - mu) * inv * g1.z + e1.z, (y[7] - mu) * inv * g1.w + e1.w};
  *(float4*)(orow + lane * 8) = o0;
  *(float4*)(orow + lane * 8 + 4) = o1;
}

extern "C" void kernel_launch(void* const* d_in, const int* in_sizes, int n_in,
                              void* d_out, int out_size, void* d_ws, size_t ws_size,
                              hipStream_t stream) {
  const float* x = (const float*)d_in[0];
  const int* mask = (const int*)d_in[1];
  const float* wq = (const float*)d_in[2];
  const float* bq = (const float*)d_in[3];
  const float* wk = (const float*)d_in[4];
  const float* bk = (const float*)d_in[5];
  const float* wv = (const float*)d_in[6];
  const float* bv = (const float*)d_in[7];
  const float* wo = (const float*)d_in[8];
  const float* bo = (const float*)d_in[9];
  const float* gamma = (const float*)d_in[10];
  const float* beta = (const float*)d_in[11];
  const float* temp = (const float*)d_in[12];
  float* out = (float*)d_out;
  char* ws = (char*)d_ws;
  const size_t MB = (size_t)1 << 20;
  unsigned short* xb  = (unsigned short*)(ws);                    // 8 MB
  unsigned short* wqb = (unsigned short*)(ws + 8 * MB);           // 0.5 MB
  unsigned short* wkb = (unsigned short*)(ws + 8 * MB + 512 * 1024);
  unsigned short* wvb = (unsigned short*)(ws + 9 * MB);
  unsigned short* wob = (unsigned short*)(ws + 9 * MB + 512 * 1024);
  unsigned short* Qb  = (unsigned short*)(ws + 10 * MB);          // 8 MB
  unsigned short* Pfb = (unsigned short*)(ws + 18 * MB);          // 8 MB bf16
  unsigned short* Vtb = (unsigned short*)(ws + 26 * MB);          // 8 MB
  unsigned short* AOb = (unsigned short*)(ws + 34 * MB);          // 8 MB
  unsigned short* Kc  = (unsigned short*)(ws + 42 * MB);          // 8 MB compacted K
  unsigned short* Vtc = (unsigned short*)(ws + 50 * MB);          // 8 MB compacted Vt
  int*            idx = (int*)(ws + 58 * MB);                     // 32 KB
  int*            rnk = (int*)(ws + 58 * MB + 64 * 1024);         // 32 KB
  int*            nkb = (int*)(ws + 58 * MB + 128 * 1024);        // 16 B

  cvt_all_kernel<<<(XN4 + 4 * WN4 + 255) / 256, 256, 0, stream>>>(
      x, wq, wk, wv, wo, xb, wqb, wkb, wvb, wob);
  rank_kernel<<<4, 64, 0, stream>>>(mask, idx, rnk, nkb);
  gemm_qkv<<<dim3(64, 4, 3), 256, 0, stream>>>(xb, wqb, wkb, wvb, bq, bk, bv, temp, rnk, Qb, Kc, Vtb);
  compact_kernel<<<dim3(64, 32), 256, 0, stream>>>(Vtb, idx, nkb, Vtc);
  attn_kernel<<<dim3(16, 32), 256, 0, stream>>>(Qb, Kc, Vtc, nkb, AOb);
  gemm_proj<<<dim3(64, 4), 256, 0, stream>>>(AOb, wob, bo, Pfb);
  ln_kernel<<<2048, 256, 0, stream>>>(Pfb, x, gamma, beta, out);
}